// Round 6
// baseline (11691.315 us; speedup 1.0000x reference)
//
#include <hip/hip_runtime.h>
#include <hip/hip_bf16.h>

// SNN: B=256, IN=1024, HID=2048, OUT=10, T=100, decay=0.9, thr=1.0, reset=0.
// Layer-pipelined: GEMM1(all t) -> LIF scan -> GEMM2(all t) -> scan -> GEMM3 -> scan.
// fp64 accumulation via v_mfma_f64_16x16x4_f64: A = spike bits as fp64 0/1,
// B = weight fragments (8 coalesced loads/4-k, 2-quad prefetch ring), C/D in
// AGPRs. Round-5 measured: MfmaUtil 80.7%, occupancy 54.7% at (256,4).
// Round-6 change: __launch_bounds__(256,6) -> 6 waves/SIMD (76 regs/wave fits
// the 512-reg unified file) to cover the ~L2-latency-edge B prefetch.
// Computation untouched -> absmax bit-identical (0.01025391).

#define B 256
#define IN_DIM 1024
#define HID 2048
#define OUT_DIM 10
#define T_STEPS 100

typedef unsigned long long ull;
typedef double d4 __attribute__((ext_vector_type(4)));

// ---------------- weight fp32 -> fp64 conversion ----------------
__global__ __launch_bounds__(256) void cvt_weights(
    const float* __restrict__ wih, const float* __restrict__ whh,
    const float* __restrict__ who,
    double* __restrict__ Wih, double* __restrict__ Whh, double* __restrict__ Who)
{
    int i = blockIdx.x * 256 + threadIdx.x;
    if (i < IN_DIM * HID) Wih[i] = (double)wih[i];
    if (i < HID * HID)    Whh[i] = (double)whh[i];
    if (i < HID * OUT_DIM) Who[i] = (double)who[i];
}

// ---------------- bit-pack input spikes ----------------
// input_bins layout [B, IN_DIM, T]; produce Xbits[(t*256+b)*16 + i/64] bit i&63.
__global__ __launch_bounds__(256) void bitpack_input(
    const float* __restrict__ inp, ull* __restrict__ Xbits)
{
    int g = blockIdx.x * 4 + (threadIdx.x >> 6);   // 0..4095 waves
    int lane = threadIdx.x & 63;
    int b = g >> 4;          // 0..255
    int ig = g & 15;         // 0..15 (i-group of 64)
    int i = ig * 64 + lane;
    const float* p = inp + ((size_t)b * IN_DIM + i) * T_STEPS;
    for (int t = 0; t < T_STEPS; ++t) {
        ull m = __ballot(p[t] > 0.5f);
        if (lane == 0) Xbits[((size_t)t * B + b) * 16 + ig] = m;
    }
}

// ---------------- MFMA fp64 bit-GEMM ----------------
// C[row, n] = sum_k bit(row,k) * W[k, n], k ascending inside each MFMA chain.
// Wave: 16 rows x 128 cols (8 MFMA tiles of 16x16). Block = 4 waves = 64 rows.
// Grid: x = rows/64, y = HID/128.
template<int WPR>
__global__ __launch_bounds__(256, 6) void gemm_mfma(
    const ull* __restrict__ bits, int bits_row_off,
    const double* __restrict__ W, double* __restrict__ C)
{
    const int lane = threadIdx.x & 63;
    const int wv = __builtin_amdgcn_readfirstlane(threadIdx.x >> 6);
    const int row0 = blockIdx.x * 64 + wv * 16;   // row base (uniform per wave)
    const int c0 = blockIdx.y * 128;
    const int li = lane & 15;        // A row / B col / D col
    const int lk = lane >> 4;        // k-within-quad (0..3); D row-group

    d4 acc[8];
#pragma unroll
    for (int t = 0; t < 8; ++t) acc[t] = (d4){0.0, 0.0, 0.0, 0.0};

    // mask stream: lane li carries row (row0+li)'s mask words (lanes 16..63 dup)
    const ull* __restrict__ mptr = bits + (size_t)(row0 + bits_row_off + li) * WPR;
    ull mvec_next = mptr[0];

    // B fragment pointer: lane loads W[kbase + lk][c0 + t*16 + li]
    const double* __restrict__ wp = W + (size_t)lk * HID + (c0 + li);

    // 2-quad prefetch ring (16 loads in flight)
    double bq0[8], bq1[8];
#pragma unroll
    for (int t = 0; t < 8; ++t) bq0[t] = wp[t * 16];
    wp += 4 * HID;
#pragma unroll
    for (int t = 0; t < 8; ++t) bq1[t] = wp[t * 16];
    wp += 4 * HID;   // ring overruns past W end by <=2 quads: lands in next ws buffer, safe

#pragma unroll 1
    for (int w = 0; w < WPR; ++w) {
        ull mvec = mvec_next;
        mvec_next = mptr[w + 1];          // 1-word overrun at end: in-ws, safe
        ull mrot = mvec >> lk;            // per-lane pre-shift by k-within-quad
#pragma unroll
        for (int qp = 0; qp < 8; ++qp) {
            {   // even quad: bits qp*8 + lk
                unsigned bbit = (unsigned)(mrot >> (qp * 8)) & 1u;
                double a = (double)bbit;
                double cur[8];
#pragma unroll
                for (int t = 0; t < 8; ++t) { cur[t] = bq0[t]; bq0[t] = wp[t * 16]; }
                wp += 4 * HID;
#pragma unroll
                for (int t = 0; t < 8; ++t)
                    acc[t] = __builtin_amdgcn_mfma_f64_16x16x4f64(a, cur[t], acc[t], 0, 0, 0);
            }
            {   // odd quad: bits qp*8 + 4 + lk
                unsigned bbit = (unsigned)(mrot >> (qp * 8 + 4)) & 1u;
                double a = (double)bbit;
                double cur[8];
#pragma unroll
                for (int t = 0; t < 8; ++t) { cur[t] = bq1[t]; bq1[t] = wp[t * 16]; }
                wp += 4 * HID;
#pragma unroll
                for (int t = 0; t < 8; ++t)
                    acc[t] = __builtin_amdgcn_mfma_f64_16x16x4f64(a, cur[t], acc[t], 0, 0, 0);
            }
        }
    }

    // D layout: row = lk*4 + r, col = t*16 + li
#pragma unroll
    for (int t = 0; t < 8; ++t) {
#pragma unroll
        for (int r = 0; r < 4; ++r) {
            C[(size_t)(row0 + lk * 4 + r) * HID + c0 + t * 16 + li] = acc[t][r];
        }
    }
}

// ---------------- output bit-GEMM: 10 columns (row-lane; small) ----------
__global__ __launch_bounds__(256) void gemm_out(
    const ull* __restrict__ bits, int bits_row_off,
    const double* __restrict__ W, double* __restrict__ C3)
{
    const int lane = threadIdx.x & 63;
    const int wave = threadIdx.x >> 6;
    const int row = blockIdx.x * 256 + wave * 64 + lane;

    double acc[OUT_DIM];
#pragma unroll
    for (int j = 0; j < OUT_DIM; ++j) acc[j] = 0.0;

    const ull* __restrict__ brow = bits + (size_t)(row + bits_row_off) * 32;
    for (int w = 0; w < 32; ++w) {
        ull m = brow[w];
        const double* __restrict__ wk = W + (size_t)(w * 64) * OUT_DIM;
#pragma unroll 4
        for (int kk = 0; kk < 64; ++kk) {
            double bd = (double)(unsigned int)(m & 1ull);
            m >>= 1;
#pragma unroll
            for (int j = 0; j < OUT_DIM; ++j)
                acc[j] = fma(bd, wk[j], acc[j]);
            wk += OUT_DIM;
        }
    }
    double* __restrict__ crow = C3 + (size_t)row * OUT_DIM;
#pragma unroll
    for (int j = 0; j < OUT_DIM; ++j) crow[j] = acc[j];
}

// ---------------- LIF scan for a hidden layer (2048 units) ----------------
__global__ __launch_bounds__(256) void lif_scan(
    const double* __restrict__ C, double* __restrict__ vstate,
    ull* __restrict__ Sbits, int bits_row_off, int Tl, int first)
{
    int g = blockIdx.x * 4 + (threadIdx.x >> 6);  // 0..8191
    int lane = threadIdx.x & 63;
    int b = g >> 5;        // 0..255
    int ng = g & 31;       // 0..31
    int n = ng * 64 + lane;
    double v = first ? 0.0 : vstate[(size_t)b * HID + n];
    for (int tl = 0; tl < Tl; ++tl) {
        double c = C[((size_t)tl * B + b) * HID + n];
        v = v * 0.9 + c;
        bool s = (v >= 1.0);
        if (s) v = 0.0;
        ull mask = __ballot(s);
        if (lane == 0)
            Sbits[((size_t)(bits_row_off + tl * B + b)) * 32 + ng] = mask;
    }
    vstate[(size_t)b * HID + n] = v;
}

// ---------------- output LIF scan + rate accumulation ----------------
__global__ __launch_bounds__(256) void lif_out(
    const double* __restrict__ C3, double* __restrict__ vstate,
    int* __restrict__ cnt_state, float* __restrict__ out, int Tl, int first)
{
    int tid = blockIdx.x * 256 + threadIdx.x;
    if (tid >= B * OUT_DIM) return;
    int b = tid / OUT_DIM, o = tid % OUT_DIM;
    double v = first ? 0.0 : vstate[tid];
    int cnt = first ? 0 : cnt_state[tid];
    for (int tl = 0; tl < Tl; ++tl) {
        double c = C3[((size_t)tl * B + b) * OUT_DIM + o];
        v = v * 0.9 + c;
        if (v >= 1.0) { cnt++; v = 0.0; }
    }
    vstate[tid] = v;
    cnt_state[tid] = cnt;
    out[tid] = (float)((double)cnt / (double)T_STEPS);
}

extern "C" void kernel_launch(void* const* d_in, const int* in_sizes, int n_in,
                              void* d_out, int out_size, void* d_ws, size_t ws_size,
                              hipStream_t stream) {
    const float* inp = (const float*)d_in[0];   // [256,1024,100]
    const float* wih = (const float*)d_in[1];   // [1024,2048]
    const float* whh = (const float*)d_in[2];   // [1,2048,2048]
    const float* who = (const float*)d_in[3];   // [2048,10]
    float* out = (float*)d_out;                 // [256,10]

    // ---- workspace layout ----
    unsigned char* p = (unsigned char*)d_ws;
    auto alloc = [&](size_t sz) -> void* {
        void* r = (void*)p;
        p += (sz + 255) & ~(size_t)255;
        return r;
    };
    double* Wih64 = (double*)alloc((size_t)IN_DIM * HID * 8);      // 16.8 MB
    double* Whh64 = (double*)alloc((size_t)HID * HID * 8);         // 33.6 MB
    double* Who64 = (double*)alloc((size_t)HID * OUT_DIM * 8);
    ull* Xbits = (ull*)alloc((size_t)T_STEPS * B * 16 * 8);        // 3.3 MB
    ull* S1    = (ull*)alloc((size_t)T_STEPS * B * 32 * 8);        // 6.6 MB
    ull* S2    = (ull*)alloc((size_t)T_STEPS * B * 32 * 8);        // 6.6 MB
    double* v1 = (double*)alloc((size_t)B * HID * 8);
    double* v2 = (double*)alloc((size_t)B * HID * 8);
    double* vo = (double*)alloc((size_t)B * OUT_DIM * 8);
    int* cnts  = (int*)alloc((size_t)B * OUT_DIM * 4);

    size_t used = (size_t)(p - (unsigned char*)d_ws);
    size_t remain = (ws_size > used) ? (ws_size - used) : 0;
    size_t per_t = (size_t)B * HID * 8 + (size_t)B * OUT_DIM * 8 + 1024;
    int CH = (int)(remain / per_t);
    if (CH > T_STEPS) CH = T_STEPS;
    if (CH < 1) CH = 1;
    double* C3 = (double*)alloc((size_t)CH * B * OUT_DIM * 8);
    double* C  = (double*)alloc((size_t)CH * B * HID * 8);

    // ---- one-time prep ----
    cvt_weights<<<(HID * HID + 255) / 256, 256, 0, stream>>>(
        wih, whh, who, Wih64, Whh64, Who64);
    bitpack_input<<<(B * (IN_DIM / 64)) / 4, 256, 0, stream>>>(inp, Xbits);

    // ---- chunked time loop ----
    for (int t0 = 0; t0 < T_STEPS; t0 += CH) {
        int L = T_STEPS - t0;
        if (L > CH) L = CH;
        int rows = L * B;            // multiple of 64
        int first = (t0 == 0) ? 1 : 0;

        // layer 1
        gemm_mfma<16><<<dim3(rows / 64, HID / 128), 256, 0, stream>>>(
            Xbits, t0 * B, Wih64, C);
        lif_scan<<<(B * (HID / 64)) / 4, 256, 0, stream>>>(
            C, v1, S1, t0 * B, L, first);

        // layer 2
        gemm_mfma<32><<<dim3(rows / 64, HID / 128), 256, 0, stream>>>(
            S1, t0 * B, Whh64, C);
        lif_scan<<<(B * (HID / 64)) / 4, 256, 0, stream>>>(
            C, v2, S2, t0 * B, L, first);

        // output layer
        gemm_out<<<rows / 256, 256, 0, stream>>>(S2, t0 * B, Who64, C3);
        lif_out<<<(B * OUT_DIM + 255) / 256, 256, 0, stream>>>(
            C3, vo, cnts, out, L, first);
    }
}

// Round 7
// 5999.262 us; speedup vs baseline: 1.9488x; 1.9488x over previous
//
#include <hip/hip_runtime.h>
#include <hip/hip_bf16.h>

// SNN: B=256, IN=1024, HID=2048, OUT=10, T=100, decay=0.9, thr=1.0, reset=0.
// Layer-pipelined: GEMM1(all t) -> LIF scan -> GEMM2(all t) -> scan -> GEMM3 -> scan.
// fp64 accumulation via v_mfma_f64_16x16x4_f64. Round-5: 16rx128c tile,
// MfmaUtil 80.7%, 2.90 ms layer-2. Round-6 (256,6) REGRESSED (allocator
// rewrote the ring; MfmaUtil 38%) -> reverted to (256,4).
// Round-7: wave tile re-aspected to 32 rows x 64 cols (2 rowgroups x 4
// col-tiles): same 8 MFMA / 32 AGPR per quad-step but 4 B-loads instead of 8
// -> halves per-CU L1 demand from the 4x-redundant B stream. k-chain order
// per output element unchanged -> absmax bit-identical (0.01025391).

#define B 256
#define IN_DIM 1024
#define HID 2048
#define OUT_DIM 10
#define T_STEPS 100

typedef unsigned long long ull;
typedef double d4 __attribute__((ext_vector_type(4)));

// ---------------- weight fp32 -> fp64 conversion ----------------
__global__ __launch_bounds__(256) void cvt_weights(
    const float* __restrict__ wih, const float* __restrict__ whh,
    const float* __restrict__ who,
    double* __restrict__ Wih, double* __restrict__ Whh, double* __restrict__ Who)
{
    int i = blockIdx.x * 256 + threadIdx.x;
    if (i < IN_DIM * HID) Wih[i] = (double)wih[i];
    if (i < HID * HID)    Whh[i] = (double)whh[i];
    if (i < HID * OUT_DIM) Who[i] = (double)who[i];
}

// ---------------- bit-pack input spikes ----------------
// input_bins layout [B, IN_DIM, T]; produce Xbits[(t*256+b)*16 + i/64] bit i&63.
__global__ __launch_bounds__(256) void bitpack_input(
    const float* __restrict__ inp, ull* __restrict__ Xbits)
{
    int g = blockIdx.x * 4 + (threadIdx.x >> 6);   // 0..4095 waves
    int lane = threadIdx.x & 63;
    int b = g >> 4;          // 0..255
    int ig = g & 15;         // 0..15 (i-group of 64)
    int i = ig * 64 + lane;
    const float* p = inp + ((size_t)b * IN_DIM + i) * T_STEPS;
    for (int t = 0; t < T_STEPS; ++t) {
        ull m = __ballot(p[t] > 0.5f);
        if (lane == 0) Xbits[((size_t)t * B + b) * 16 + ig] = m;
    }
}

// ---------------- MFMA fp64 bit-GEMM (32r x 64c per wave) ----------------
// C[row, n] = sum_k bit(row,k) * W[k, n], k ascending inside each MFMA chain.
// Wave: 2 rowgroups x 4 col-tiles of 16x16. Block = 4 waves = 128 rows.
// Grid: x = rows/128, y = HID/64.
template<int WPR>
__global__ __launch_bounds__(256, 4) void gemm_mfma(
    const ull* __restrict__ bits, int bits_row_off,
    const double* __restrict__ W, double* __restrict__ C)
{
    const int lane = threadIdx.x & 63;
    const int wv = __builtin_amdgcn_readfirstlane(threadIdx.x >> 6);
    const int row0 = blockIdx.x * 128 + wv * 32;  // row base (uniform per wave)
    const int c0 = blockIdx.y * 64;
    const int li = lane & 15;        // A row-in-group / B col / D col
    const int lk = lane >> 4;        // k-within-quad (0..3); D row-group

    d4 acc[2][4];
#pragma unroll
    for (int g = 0; g < 2; ++g)
#pragma unroll
        for (int t = 0; t < 4; ++t) acc[g][t] = (d4){0.0, 0.0, 0.0, 0.0};

    // mask streams: lane li carries rows row0+li and row0+16+li (dup across lk)
    const ull* __restrict__ mptr0 = bits + (size_t)(row0 + bits_row_off + li) * WPR;
    const ull* __restrict__ mptr1 = mptr0 + (size_t)16 * WPR;
    ull mnext0 = mptr0[0];
    ull mnext1 = mptr1[0];

    // B fragment pointer: lane loads W[kbase + lk][c0 + t*16 + li]
    const double* __restrict__ wp = W + (size_t)lk * HID + (c0 + li);

    // 2-quad prefetch ring (8 loads in flight, consumed ~1024 cy later)
    double bq0[4], bq1[4];
#pragma unroll
    for (int t = 0; t < 4; ++t) bq0[t] = wp[t * 16];
    wp += 4 * HID;
#pragma unroll
    for (int t = 0; t < 4; ++t) bq1[t] = wp[t * 16];
    wp += 4 * HID;   // ring overruns past W end by <=2 quads: lands in next ws buffer, safe

#pragma unroll 1
    for (int w = 0; w < WPR; ++w) {
        ull mvec0 = mnext0, mvec1 = mnext1;
        mnext0 = mptr0[w + 1];            // 1-word overrun at end: in-ws, safe
        mnext1 = mptr1[w + 1];
        ull mrot0 = mvec0 >> lk;          // per-lane pre-shift by k-within-quad
        ull mrot1 = mvec1 >> lk;
#pragma unroll
        for (int qp = 0; qp < 8; ++qp) {
            {   // even quad: bits qp*8 + lk
                double a0 = (double)((unsigned)(mrot0 >> (qp * 8)) & 1u);
                double a1 = (double)((unsigned)(mrot1 >> (qp * 8)) & 1u);
                double cur[4];
#pragma unroll
                for (int t = 0; t < 4; ++t) { cur[t] = bq0[t]; bq0[t] = wp[t * 16]; }
                wp += 4 * HID;
#pragma unroll
                for (int t = 0; t < 4; ++t) {
                    acc[0][t] = __builtin_amdgcn_mfma_f64_16x16x4f64(a0, cur[t], acc[0][t], 0, 0, 0);
                    acc[1][t] = __builtin_amdgcn_mfma_f64_16x16x4f64(a1, cur[t], acc[1][t], 0, 0, 0);
                }
            }
            {   // odd quad: bits qp*8 + 4 + lk
                double a0 = (double)((unsigned)(mrot0 >> (qp * 8 + 4)) & 1u);
                double a1 = (double)((unsigned)(mrot1 >> (qp * 8 + 4)) & 1u);
                double cur[4];
#pragma unroll
                for (int t = 0; t < 4; ++t) { cur[t] = bq1[t]; bq1[t] = wp[t * 16]; }
                wp += 4 * HID;
#pragma unroll
                for (int t = 0; t < 4; ++t) {
                    acc[0][t] = __builtin_amdgcn_mfma_f64_16x16x4f64(a0, cur[t], acc[0][t], 0, 0, 0);
                    acc[1][t] = __builtin_amdgcn_mfma_f64_16x16x4f64(a1, cur[t], acc[1][t], 0, 0, 0);
                }
            }
        }
    }

    // D layout: row = g*16 + lk*4 + r, col = t*16 + li
#pragma unroll
    for (int g = 0; g < 2; ++g) {
#pragma unroll
        for (int t = 0; t < 4; ++t) {
#pragma unroll
            for (int r = 0; r < 4; ++r) {
                C[(size_t)(row0 + g * 16 + lk * 4 + r) * HID + c0 + t * 16 + li] = acc[g][t][r];
            }
        }
    }
}

// ---------------- output bit-GEMM: 10 columns (row-lane; small) ----------
__global__ __launch_bounds__(256) void gemm_out(
    const ull* __restrict__ bits, int bits_row_off,
    const double* __restrict__ W, double* __restrict__ C3)
{
    const int lane = threadIdx.x & 63;
    const int wave = threadIdx.x >> 6;
    const int row = blockIdx.x * 256 + wave * 64 + lane;

    double acc[OUT_DIM];
#pragma unroll
    for (int j = 0; j < OUT_DIM; ++j) acc[j] = 0.0;

    const ull* __restrict__ brow = bits + (size_t)(row + bits_row_off) * 32;
    for (int w = 0; w < 32; ++w) {
        ull m = brow[w];
        const double* __restrict__ wk = W + (size_t)(w * 64) * OUT_DIM;
#pragma unroll 4
        for (int kk = 0; kk < 64; ++kk) {
            double bd = (double)(unsigned int)(m & 1ull);
            m >>= 1;
#pragma unroll
            for (int j = 0; j < OUT_DIM; ++j)
                acc[j] = fma(bd, wk[j], acc[j]);
            wk += OUT_DIM;
        }
    }
    double* __restrict__ crow = C3 + (size_t)row * OUT_DIM;
#pragma unroll
    for (int j = 0; j < OUT_DIM; ++j) crow[j] = acc[j];
}

// ---------------- LIF scan for a hidden layer (2048 units) ----------------
__global__ __launch_bounds__(256) void lif_scan(
    const double* __restrict__ C, double* __restrict__ vstate,
    ull* __restrict__ Sbits, int bits_row_off, int Tl, int first)
{
    int g = blockIdx.x * 4 + (threadIdx.x >> 6);  // 0..8191
    int lane = threadIdx.x & 63;
    int b = g >> 5;        // 0..255
    int ng = g & 31;       // 0..31
    int n = ng * 64 + lane;
    double v = first ? 0.0 : vstate[(size_t)b * HID + n];
    for (int tl = 0; tl < Tl; ++tl) {
        double c = C[((size_t)tl * B + b) * HID + n];
        v = v * 0.9 + c;
        bool s = (v >= 1.0);
        if (s) v = 0.0;
        ull mask = __ballot(s);
        if (lane == 0)
            Sbits[((size_t)(bits_row_off + tl * B + b)) * 32 + ng] = mask;
    }
    vstate[(size_t)b * HID + n] = v;
}

// ---------------- output LIF scan + rate accumulation ----------------
__global__ __launch_bounds__(256) void lif_out(
    const double* __restrict__ C3, double* __restrict__ vstate,
    int* __restrict__ cnt_state, float* __restrict__ out, int Tl, int first)
{
    int tid = blockIdx.x * 256 + threadIdx.x;
    if (tid >= B * OUT_DIM) return;
    int b = tid / OUT_DIM, o = tid % OUT_DIM;
    double v = first ? 0.0 : vstate[tid];
    int cnt = first ? 0 : cnt_state[tid];
    for (int tl = 0; tl < Tl; ++tl) {
        double c = C3[((size_t)tl * B + b) * OUT_DIM + o];
        v = v * 0.9 + c;
        if (v >= 1.0) { cnt++; v = 0.0; }
    }
    vstate[tid] = v;
    cnt_state[tid] = cnt;
    out[tid] = (float)((double)cnt / (double)T_STEPS);
}

extern "C" void kernel_launch(void* const* d_in, const int* in_sizes, int n_in,
                              void* d_out, int out_size, void* d_ws, size_t ws_size,
                              hipStream_t stream) {
    const float* inp = (const float*)d_in[0];   // [256,1024,100]
    const float* wih = (const float*)d_in[1];   // [1024,2048]
    const float* whh = (const float*)d_in[2];   // [1,2048,2048]
    const float* who = (const float*)d_in[3];   // [2048,10]
    float* out = (float*)d_out;                 // [256,10]

    // ---- workspace layout ----
    unsigned char* p = (unsigned char*)d_ws;
    auto alloc = [&](size_t sz) -> void* {
        void* r = (void*)p;
        p += (sz + 255) & ~(size_t)255;
        return r;
    };
    double* Wih64 = (double*)alloc((size_t)IN_DIM * HID * 8);      // 16.8 MB
    double* Whh64 = (double*)alloc((size_t)HID * HID * 8);         // 33.6 MB
    double* Who64 = (double*)alloc((size_t)HID * OUT_DIM * 8);
    ull* Xbits = (ull*)alloc((size_t)T_STEPS * B * 16 * 8);        // 3.3 MB
    ull* S1    = (ull*)alloc((size_t)T_STEPS * B * 32 * 8);        // 6.6 MB
    ull* S2    = (ull*)alloc((size_t)T_STEPS * B * 32 * 8);        // 6.6 MB
    double* v1 = (double*)alloc((size_t)B * HID * 8);
    double* v2 = (double*)alloc((size_t)B * HID * 8);
    double* vo = (double*)alloc((size_t)B * OUT_DIM * 8);
    int* cnts  = (int*)alloc((size_t)B * OUT_DIM * 4);

    size_t used = (size_t)(p - (unsigned char*)d_ws);
    size_t remain = (ws_size > used) ? (ws_size - used) : 0;
    size_t per_t = (size_t)B * HID * 8 + (size_t)B * OUT_DIM * 8 + 1024;
    int CH = (int)(remain / per_t);
    if (CH > T_STEPS) CH = T_STEPS;
    if (CH < 1) CH = 1;
    double* C3 = (double*)alloc((size_t)CH * B * OUT_DIM * 8);
    double* C  = (double*)alloc((size_t)CH * B * HID * 8);

    // ---- one-time prep ----
    cvt_weights<<<(HID * HID + 255) / 256, 256, 0, stream>>>(
        wih, whh, who, Wih64, Whh64, Who64);
    bitpack_input<<<(B * (IN_DIM / 64)) / 4, 256, 0, stream>>>(inp, Xbits);

    // ---- chunked time loop ----
    for (int t0 = 0; t0 < T_STEPS; t0 += CH) {
        int L = T_STEPS - t0;
        if (L > CH) L = CH;
        int rows = L * B;            // multiple of 128
        int first = (t0 == 0) ? 1 : 0;

        // layer 1
        gemm_mfma<16><<<dim3(rows / 128, HID / 64), 256, 0, stream>>>(
            Xbits, t0 * B, Wih64, C);
        lif_scan<<<(B * (HID / 64)) / 4, 256, 0, stream>>>(
            C, v1, S1, t0 * B, L, first);

        // layer 2
        gemm_mfma<32><<<dim3(rows / 128, HID / 64), 256, 0, stream>>>(
            S1, t0 * B, Whh64, C);
        lif_scan<<<(B * (HID / 64)) / 4, 256, 0, stream>>>(
            C, v2, S2, t0 * B, L, first);

        // output layer
        gemm_out<<<rows / 256, 256, 0, stream>>>(S2, t0 * B, Who64, C3);
        lif_out<<<(B * OUT_DIM + 255) / 256, 256, 0, stream>>>(
            C3, vo, cnts, out, L, first);
    }
}